// Round 1
// 644.698 us; speedup vs baseline: 1.3665x; 1.3665x over previous
//
#include <hip/hip_runtime.h>
#include <stdint.h>

// Problem dims
#define Bg 256
#define Tg 64
#define Pg 10
#define NG 8   // graphs per sgcn block

typedef _Float16 half2v __attribute__((ext_vector_type(2)));

// fp16 packed dot product with fp32 accumulate: c + a.x*b.x + a.y*b.y
__device__ __forceinline__ float dot2(uint32_t a, uint32_t b, float c) {
#if __has_builtin(__builtin_amdgcn_fdot2)
    return __builtin_amdgcn_fdot2(__builtin_bit_cast(half2v, a),
                                  __builtin_bit_cast(half2v, b), c, false);
#else
    float d;
    asm("v_dot2_f32_f16 %0, %1, %2, %3"
        : "=v"(d) : "v"(a), "v"(b), "v"(c));
    return d;
#endif
}

__device__ __forceinline__ uint32_t pkh2(float lo, float hi) {
    half2v h; h.x = (_Float16)lo; h.y = (_Float16)hi;
    return __builtin_bit_cast(uint32_t, h);
}
__device__ __forceinline__ uint16_t f2h(float f) {
    _Float16 h = (_Float16)f;
    return __builtin_bit_cast(uint16_t, h);
}
__device__ __forceinline__ float sigmoidf_(float x) {
    return 1.0f / (1.0f + __expf(-x));
}
__device__ __forceinline__ float fast_tanh(float x) {
    float e = __expf(2.0f * x);
    return (e - 1.0f) / (e + 1.0f);
}

// ---------------------------------------------------------------------------
// SGCN v4: base layer fp32 (exact), deep layers packed-fp16 + v_dot2.
// H stored as [g][j][cpair][2]{hp,hn} u32; deep weights restaged packed-fp16
// with the self-block (w7) pre-merged into w5/w6 per sign (6 blocks not 7).
// LDS instrs/thread/deep-layer: 544 -> 176; deep VALU halved.
// ---------------------------------------------------------------------------
__global__ __launch_bounds__(512) void sgcn_kernel(
    const float* __restrict__ x,
    const float* __restrict__ A_pos,
    const float* __restrict__ A_neg,
    const float* __restrict__ Wpb,
    const float* __restrict__ bpb,
    const float* __restrict__ Wnb,
    const float* __restrict__ bnb,
    const float* __restrict__ Wpd,
    const float* __restrict__ bpd,
    const float* __restrict__ Wnd,
    const float* __restrict__ bnd,
    uint32_t* __restrict__ z)
{
    __shared__ __align__(16) float WL[16384];            // 64 KB: base fp32 / deep packed fp16
    __shared__ __align__(16) float As[NG][2][10][10];    // 6.4 KB norm. adj
    __shared__ float rsv[NG][2][10];
    __shared__ __align__(16) float Xs[NG][10][128];      // 40 KB
    __shared__ __align__(16) uint32_t H16a[NG][10][16][2]; // 10 KB (ping) packed fp16
    __shared__ __align__(16) uint32_t H16b[NG][10][16][2]; // 10 KB (pong)

    const int tid = threadIdx.x;
    const int bt0 = blockIdx.x * NG;
    const int g = tid >> 6;          // wave-uniform graph
    const int s = (tid >> 5) & 1;    // sign
    const int k = tid & 31;          // output column

    // ---- stage base weights [s][d(0..255)][k], coalesced float4 ----
    {
        const float4* wp = reinterpret_cast<const float4*>(Wpb);
        const float4* wn = reinterpret_cast<const float4*>(Wnb);
        float4* wl = reinterpret_cast<float4*>(WL);
        for (int e = tid; e < 4096; e += 512)
            wl[e] = (e < 2048) ? wp[e] : wn[e - 2048];
    }
    // ---- load X ----
    {
        float4* xs = reinterpret_cast<float4*>(&Xs[0][0][0]);
        for (int e = tid; e < NG * 320; e += 512) {
            int gg = e / 320, r = e - gg * 320;
            xs[e] = reinterpret_cast<const float4*>(
                x + (size_t)(bt0 + gg) * 1280)[r];
        }
    }
    // ---- load raw adjacencies ----
    for (int e = tid; e < NG * 200; e += 512) {
        int gg = e / 200, r = e - gg * 200;
        int sg = r / 100, rr = r - sg * 100;
        (&As[gg][sg][0][0])[rr] =
            (sg ? A_neg : A_pos)[(size_t)(bt0 + gg) * 100 + rr];
    }
    __syncthreads();
    if (tid < NG * 20) {
        int gg = tid / 20, r = tid % 20, sg = r / 10, i = r % 10;
        float sum = 0.f;
        #pragma unroll
        for (int j = 0; j < 10; ++j) sum += As[gg][sg][i][j];
        rsv[gg][sg][i] = 1.0f / (sum + 1e-8f);
    }
    __syncthreads();
    for (int e = tid; e < NG * 200; e += 512) {
        int gg = e / 200, r = e - gg * 200;
        int sg = r / 100, rr = r - sg * 100;
        As[gg][sg][rr / 10][rr % 10] *= rsv[gg][sg][rr / 10];
    }
    __syncthreads();

    // per-thread packed output slot: u16 index (i stride 64)
    const int hslot = g * 640 + (k >> 1) * 4 + s * 2 + (k & 1);

    // ---- base layer (fp32 exact): Y=X@Wtop, Z=X@Wbot; H=tanh(An@Y + Z + b) ----
    {
        float accY[10], accZ[10];
        #pragma unroll
        for (int i = 0; i < 10; ++i) { accY[i] = 0.f; accZ[i] = 0.f; }
        const float* Wt = &WL[s * 8192 + k];
        for (int d = 0; d < 128; d += 4) {
            float wt0 = Wt[(d + 0) * 32], wt1 = Wt[(d + 1) * 32];
            float wt2 = Wt[(d + 2) * 32], wt3 = Wt[(d + 3) * 32];
            float wb0 = Wt[(d + 128) * 32], wb1 = Wt[(d + 129) * 32];
            float wb2 = Wt[(d + 130) * 32], wb3 = Wt[(d + 131) * 32];
            #pragma unroll
            for (int i = 0; i < 10; ++i) {
                float4 xv = *reinterpret_cast<const float4*>(&Xs[g][i][d]);
                accY[i] += xv.x * wt0 + xv.y * wt1 + xv.z * wt2 + xv.w * wt3;
                accZ[i] += xv.x * wb0 + xv.y * wb1 + xv.z * wb2 + xv.w * wb3;
            }
        }
        float bb = (s ? bnb : bpb)[k];
        uint16_t* Hw = reinterpret_cast<uint16_t*>(&H16a[0][0][0][0]);
        const float2* Ar = reinterpret_cast<const float2*>(&As[g][s][0][0]);
        #pragma unroll
        for (int i = 0; i < 10; ++i) {
            float acc = accZ[i] + bb;
            #pragma unroll
            for (int m = 0; m < 5; ++m) {
                float2 a2 = Ar[i * 5 + m];
                acc += a2.x * accY[2 * m] + a2.y * accY[2 * m + 1];
            }
            Hw[hslot + i * 64] = f2h(fast_tanh(acc));
        }
    }
    __syncthreads();

    // ---- two deep layers: packed fp16 + dot2, ping-pong H16a/H16b ----
    uint32_t* WLu = reinterpret_cast<uint32_t*>(WL);
    for (int l = 0; l < 2; ++l) {
        // restage deep weights packed fp16: [s][blk0..5][cpair0..15][k]
        // blk4 = w5 + (s==0 ? w7 : 0)  (hp input), blk5 = w6 + (s==1 ? w7 : 0) (hn)
        for (int e = tid; e < 6144; e += 512) {
            int ss = e >= 3072;
            int r = e - ss * 3072;
            int blk = r >> 9;
            int r2 = r & 511;
            int cp = r2 >> 5;
            int kk = r2 & 31;
            const float* Ws = (ss ? Wnd : Wpd) + l * 7168;
            int rk = blk * 32 + 2 * cp;
            float f0 = Ws[rk * 32 + kk];
            float f1 = Ws[(rk + 1) * 32 + kk];
            if (blk >= 4 && ((blk == 4) == (ss == 0))) {
                f0 += Ws[(192 + 2 * cp) * 32 + kk];
                f1 += Ws[(193 + 2 * cp) * 32 + kk];
            }
            WLu[e] = pkh2(f0, f1);
        }
        __syncthreads();

        const uint32_t* Hin = l ? &H16b[0][0][0][0] : &H16a[0][0][0][0];
        uint16_t* Hout16 = reinterpret_cast<uint16_t*>(
            l ? &H16a[0][0][0][0] : &H16b[0][0][0][0]);

        float U12[10], U34[10], Dd[10];
        #pragma unroll
        for (int i = 0; i < 10; ++i) { U12[i] = 0.f; U34[i] = 0.f; Dd[i] = 0.f; }
        const uint32_t* Wd = WLu + s * 3072 + k;   // + blk*512 + cp*32
        const uint32_t* Hg = Hin + g * 320;        // [j][cp][2], j stride 32

        for (int cp = 0; cp < 16; cp += 2) {
            const int o = cp * 32;
            uint32_t w00 = Wd[0 * 512 + o], w01 = Wd[0 * 512 + o + 32];
            uint32_t w10 = Wd[1 * 512 + o], w11 = Wd[1 * 512 + o + 32];
            uint32_t w20 = Wd[2 * 512 + o], w21 = Wd[2 * 512 + o + 32];
            uint32_t w30 = Wd[3 * 512 + o], w31 = Wd[3 * 512 + o + 32];
            uint32_t w40 = Wd[4 * 512 + o], w41 = Wd[4 * 512 + o + 32];
            uint32_t w50 = Wd[5 * 512 + o], w51 = Wd[5 * 512 + o + 32];
            #pragma unroll
            for (int j = 0; j < 10; ++j) {
                // hv = {hp(cp), hn(cp), hp(cp+1), hn(cp+1)}
                uint4 hv = *reinterpret_cast<const uint4*>(Hg + j * 32 + cp * 2);
                U12[j] = dot2(hv.x, w00, U12[j]);
                U12[j] = dot2(hv.z, w01, U12[j]);
                U12[j] = dot2(hv.y, w10, U12[j]);
                U12[j] = dot2(hv.w, w11, U12[j]);
                U34[j] = dot2(hv.x, w20, U34[j]);
                U34[j] = dot2(hv.z, w21, U34[j]);
                U34[j] = dot2(hv.y, w30, U34[j]);
                U34[j] = dot2(hv.w, w31, U34[j]);
                Dd[j]  = dot2(hv.x, w40, Dd[j]);
                Dd[j]  = dot2(hv.z, w41, Dd[j]);
                Dd[j]  = dot2(hv.y, w50, Dd[j]);
                Dd[j]  = dot2(hv.w, w51, Dd[j]);
            }
        }
        float bb = (s ? bnd : bpd)[l * 32 + k];
        const float2* Ap = reinterpret_cast<const float2*>(&As[g][0][0][0]);
        const float2* An = reinterpret_cast<const float2*>(&As[g][1][0][0]);
        #pragma unroll
        for (int i = 0; i < 10; ++i) {
            float acc = Dd[i] + bb;
            #pragma unroll
            for (int m = 0; m < 5; ++m) {
                float2 ap = Ap[i * 5 + m], an = An[i * 5 + m];
                acc += ap.x * U12[2 * m] + ap.y * U12[2 * m + 1]
                     + an.x * U34[2 * m] + an.y * U34[2 * m + 1];
            }
            Hout16[hslot + i * 64] = f2h(fast_tanh(acc));
        }
        __syncthreads();
    }

    // ---- z = cat([h_pos, h_neg], -1) as packed fp16 u32 (final H in H16a) ----
    {
        uint32_t* zb = z + (size_t)bt0 * 320;
        const uint32_t* Hf = &H16a[0][0][0][0];
        for (int e = tid; e < NG * 320; e += 512) {
            int gg = e / 320, r = e - gg * 320;
            int i = r >> 5, m = r & 31;
            zb[e] = Hf[gg * 320 + i * 32 + (m & 15) * 2 + (m >> 4)];
        }
    }
}

// ---------------------------------------------------------------------------
// LSTM v4: packed-fp16 z/h in LDS + v_dot2 gates. Weights stay packed fp16 in
// the same 64 VGPRs (no per-step unpack). LDS reads/step: 64 b128 -> 32 b128.
// VALU/step: ~410 -> ~160. No min-wave launch bound (R6 lesson: spills).
// ---------------------------------------------------------------------------
__global__ __launch_bounds__(256) void lstm_kernel(
    const uint32_t* __restrict__ zin,
    const float* __restrict__ W_ih,
    const float* __restrict__ W_hh,
    const float* __restrict__ b_ih,
    const float* __restrict__ b_hh,
    float* __restrict__ out)
{
    __shared__ __align__(16) uint32_t zh[2][64];  // per game: [z 32 u32 | h 32 u32] packed fp16
    __shared__ float gbuf[2][256];                // gate pre-activations fp32

    const int tid = threadIdx.x;
    const int p   = blockIdx.x % 10;
    const int b0  = (blockIdx.x / 10) * 2;

    uint32_t wreg[64];   // packed fp16: [z-pairs 0..31 | h-pairs 32..63]
    {
        const float4* wi4 = reinterpret_cast<const float4*>(
            W_ih + ((size_t)p * 256 + tid) * 64);
        const float4* wh4 = reinterpret_cast<const float4*>(
            W_hh + ((size_t)p * 256 + tid) * 64);
        #pragma unroll
        for (int m = 0; m < 16; ++m) {
            float4 v = wi4[m];
            wreg[m * 2 + 0] = pkh2(v.x, v.y);
            wreg[m * 2 + 1] = pkh2(v.z, v.w);
        }
        #pragma unroll
        for (int m = 0; m < 16; ++m) {
            float4 v = wh4[m];
            wreg[32 + m * 2 + 0] = pkh2(v.x, v.y);
            wreg[32 + m * 2 + 1] = pkh2(v.z, v.w);
        }
    }
    const float bias = b_ih[p * 256 + tid] + b_hh[p * 256 + tid];
    const int n = (tid >> 6) & 1, kk = tid & 63;   // roles for tid<128
    float creg = 0.f;
    if (tid < 64) zh[tid >> 5][32 + (tid & 31)] = 0u;   // h := 0
    __syncthreads();

    for (int t = 0; t < 64; ++t) {
        if (tid < 64)
            zh[tid >> 5][tid & 31] =
                zin[((size_t)(b0 + (tid >> 5)) * 64 + t) * 320 + p * 32 + (tid & 31)];
        __syncthreads();

        // gates: thread g computes gate row g for both games (4 acc chains)
        float a0 = bias, a0b = 0.f, a1 = bias, a1b = 0.f;
        #pragma unroll
        for (int q = 0; q < 16; ++q) {
            uint4 z0 = *reinterpret_cast<const uint4*>(&zh[0][q * 4]);
            uint4 z1 = *reinterpret_cast<const uint4*>(&zh[1][q * 4]);
            a0  = dot2(z0.x, wreg[q * 4 + 0], a0);
            a0b = dot2(z0.y, wreg[q * 4 + 1], a0b);
            a0  = dot2(z0.z, wreg[q * 4 + 2], a0);
            a0b = dot2(z0.w, wreg[q * 4 + 3], a0b);
            a1  = dot2(z1.x, wreg[q * 4 + 0], a1);
            a1b = dot2(z1.y, wreg[q * 4 + 1], a1b);
            a1  = dot2(z1.z, wreg[q * 4 + 2], a1);
            a1b = dot2(z1.w, wreg[q * 4 + 3], a1b);
        }
        gbuf[0][tid] = a0 + a0b; gbuf[1][tid] = a1 + a1b;
        __syncthreads();

        if (tid < 128) {
            float gi = gbuf[n][kk];
            float gf = gbuf[n][64 + kk];
            float gg = gbuf[n][128 + kk];
            float go = gbuf[n][192 + kk];
            float cn = sigmoidf_(gf) * creg + sigmoidf_(gi) * fast_tanh(gg);
            float hn = sigmoidf_(go) * fast_tanh(cn);
            creg = cn;
            reinterpret_cast<uint16_t*>(&zh[0][0])[n * 128 + 64 + kk] = f2h(hn);
            out[((size_t)(b0 + n) * 64 + t) * 640 + p * 64 + kk] = hn;
        }
        __syncthreads();
    }
}

extern "C" void kernel_launch(void* const* d_in, const int* in_sizes, int n_in,
                              void* d_out, int out_size, void* d_ws, size_t ws_size,
                              hipStream_t stream) {
    const float* x     = (const float*)d_in[0];
    const float* A_pos = (const float*)d_in[1];
    const float* A_neg = (const float*)d_in[2];
    const float* Wpb   = (const float*)d_in[3];
    const float* bpb   = (const float*)d_in[4];
    const float* Wnb   = (const float*)d_in[5];
    const float* bnb   = (const float*)d_in[6];
    const float* Wpd   = (const float*)d_in[7];
    const float* bpd   = (const float*)d_in[8];
    const float* Wnd   = (const float*)d_in[9];
    const float* bnd   = (const float*)d_in[10];
    const float* Wih   = (const float*)d_in[11];
    const float* Whh   = (const float*)d_in[12];
    const float* bih   = (const float*)d_in[13];
    const float* bhh   = (const float*)d_in[14];

    uint32_t* z = (uint32_t*)d_ws;     // [B,T,P,32] packed fp16 pairs = 20 MB
    float* out  = (float*)d_out;       // [B,T,P,64] fp32 = 40 MB

    sgcn_kernel<<<(Bg * Tg) / NG, 512, 0, stream>>>(
        x, A_pos, A_neg, Wpb, bpb, Wnb, bnb, Wpd, bpd, Wnd, bnd, z);
    lstm_kernel<<<(Bg / 2) * Pg, 256, 0, stream>>>(
        z, Wih, Whh, bih, bhh, out);
}

// Round 2
// 518.040 us; speedup vs baseline: 1.7007x; 1.2445x over previous
//
#include <hip/hip_runtime.h>
#include <stdint.h>

// Problem dims
#define Bg 256
#define Tg 64
#define Pg 10
#define NG 8   // graphs per sgcn block

typedef _Float16 half2v __attribute__((ext_vector_type(2)));

// fp16 packed dot product with fp32 accumulate: c + a.x*b.x + a.y*b.y
__device__ __forceinline__ float dot2(uint32_t a, uint32_t b, float c) {
#if __has_builtin(__builtin_amdgcn_fdot2)
    return __builtin_amdgcn_fdot2(__builtin_bit_cast(half2v, a),
                                  __builtin_bit_cast(half2v, b), c, false);
#else
    float d;
    asm("v_dot2_f32_f16 %0, %1, %2, %3"
        : "=v"(d) : "v"(a), "v"(b), "v"(c));
    return d;
#endif
}

__device__ __forceinline__ uint32_t pkh2(float lo, float hi) {
    half2v h; h.x = (_Float16)lo; h.y = (_Float16)hi;
    return __builtin_bit_cast(uint32_t, h);
}
__device__ __forceinline__ uint16_t f2h(float f) {
    _Float16 h = (_Float16)f;
    return __builtin_bit_cast(uint16_t, h);
}
__device__ __forceinline__ float sigmoidf_(float x) {
    return 1.0f / (1.0f + __expf(-x));
}
__device__ __forceinline__ float fast_tanh(float x) {
    float e = __expf(2.0f * x);
    return (e - 1.0f) / (e + 1.0f);
}

// ---------------------------------------------------------------------------
// SGCN v5: fully packed-fp16 + v_dot2 (base AND deep). LDS 80.7 KB -> 2
// blocks/CU (was 134 KB / 1 block, 23% occupancy). All LDS weight reads are
// per-lane-consecutive-16B-chunk b128 (conflict-free); X/H reads broadcast.
// Per-thread: VALU ~9k->~4.5k, LDS instrs ~930->~550.
// ---------------------------------------------------------------------------
__global__ __launch_bounds__(512) void sgcn_kernel(
    const float* __restrict__ x,
    const float* __restrict__ A_pos,
    const float* __restrict__ A_neg,
    const float* __restrict__ Wpb,
    const float* __restrict__ bpb,
    const float* __restrict__ Wnb,
    const float* __restrict__ bnb,
    const float* __restrict__ Wpd,
    const float* __restrict__ bpd,
    const float* __restrict__ Wnd,
    const float* __restrict__ bnd,
    uint32_t* __restrict__ z)
{
    __shared__ __align__(16) uint32_t WLu[8192];           // 32 KB packed fp16 weights
    __shared__ __align__(16) float As[NG][2][10][10];      // 6.4 KB norm. adj
    __shared__ float rsv[NG][2][10];                       // 640 B
    __shared__ __align__(16) uint32_t Xsu[NG][10][64];     // 20 KB packed fp16 X
    __shared__ __align__(16) uint32_t H16a[NG][10][16][2]; // 10 KB (ping)
    __shared__ __align__(16) uint32_t H16b[NG][10][16][2]; // 10 KB (pong)
    // total = 80,768 B -> 2 blocks/CU (<= 160 KB)

    const int tid = threadIdx.x;
    const int bt0 = blockIdx.x * NG;
    const int g = tid >> 6;          // wave-uniform graph
    const int s = (tid >> 5) & 1;    // sign
    const int k = tid & 31;          // output column

    // ---- stage base weights packed fp16: [tb][d2g][s*32+k][j] ----
    // u32 idx = tb*4096 + d2g*256 + ln*4 + j  (d2 = d2g*4+j pairs along d)
    for (int e = tid; e < 8192; e += 512) {
        int tb = e >> 12;
        int r = e & 4095;
        int d2g = r >> 8;
        int r2 = r & 255;
        int ln = r2 >> 2;
        int j  = r2 & 3;
        int ss = ln >> 5, kk = ln & 31;
        int d2 = d2g * 4 + j;
        const float* Ws = (ss ? Wnb : Wpb) + (tb * 128 + 2 * d2) * 32 + kk;
        WLu[e] = pkh2(Ws[0], Ws[32]);
    }
    // ---- stage X packed fp16 ----
    for (int e = tid; e < NG * 640; e += 512) {
        int gg = e / 640, r = e - gg * 640;
        const float2* xp = reinterpret_cast<const float2*>(
            x + (size_t)(bt0 + gg) * 1280);
        float2 v = xp[r];
        (&Xsu[0][0][0])[e] = pkh2(v.x, v.y);
    }
    // ---- load raw adjacencies ----
    for (int e = tid; e < NG * 200; e += 512) {
        int gg = e / 200, r = e - gg * 200;
        int sg = r / 100, rr = r - sg * 100;
        (&As[gg][sg][0][0])[rr] =
            (sg ? A_neg : A_pos)[(size_t)(bt0 + gg) * 100 + rr];
    }
    __syncthreads();
    if (tid < NG * 20) {
        int gg = tid / 20, r = tid % 20, sg = r / 10, i = r % 10;
        float sum = 0.f;
        #pragma unroll
        for (int j = 0; j < 10; ++j) sum += As[gg][sg][i][j];
        rsv[gg][sg][i] = 1.0f / (sum + 1e-8f);
    }
    __syncthreads();
    for (int e = tid; e < NG * 200; e += 512) {
        int gg = e / 200, r = e - gg * 200;
        int sg = r / 100, rr = r - sg * 100;
        As[gg][sg][rr / 10][rr % 10] *= rsv[gg][sg][rr / 10];
    }
    __syncthreads();

    // per-thread packed output slot: u16 index (i stride 64)
    const int hslot = g * 640 + (k >> 1) * 4 + s * 2 + (k & 1);

    // ---- base layer fp16 dot2: Y=X@Wtop, Z=X@Wbot; H=tanh(An@Y + Z + b) ----
    {
        float accY[10], accZ[10];
        #pragma unroll
        for (int i = 0; i < 10; ++i) { accY[i] = 0.f; accZ[i] = 0.f; }
        const uint32_t* Wt = &WLu[(s * 32 + k) * 4];
        const uint32_t* Xg = &Xsu[g][0][0];
        for (int d2g = 0; d2g < 16; ++d2g) {
            uint4 wt = *reinterpret_cast<const uint4*>(Wt + d2g * 256);
            uint4 wb = *reinterpret_cast<const uint4*>(Wt + 4096 + d2g * 256);
            #pragma unroll
            for (int i = 0; i < 10; ++i) {
                uint4 xv = *reinterpret_cast<const uint4*>(Xg + i * 64 + d2g * 4);
                accY[i] = dot2(xv.x, wt.x, accY[i]);
                accY[i] = dot2(xv.y, wt.y, accY[i]);
                accY[i] = dot2(xv.z, wt.z, accY[i]);
                accY[i] = dot2(xv.w, wt.w, accY[i]);
                accZ[i] = dot2(xv.x, wb.x, accZ[i]);
                accZ[i] = dot2(xv.y, wb.y, accZ[i]);
                accZ[i] = dot2(xv.z, wb.z, accZ[i]);
                accZ[i] = dot2(xv.w, wb.w, accZ[i]);
            }
        }
        float bb = (s ? bnb : bpb)[k];
        uint16_t* Hw = reinterpret_cast<uint16_t*>(&H16a[0][0][0][0]);
        const float2* Ar = reinterpret_cast<const float2*>(&As[g][s][0][0]);
        #pragma unroll
        for (int i = 0; i < 10; ++i) {
            float acc = accZ[i] + bb;
            #pragma unroll
            for (int m = 0; m < 5; ++m) {
                float2 a2 = Ar[i * 5 + m];
                acc += a2.x * accY[2 * m] + a2.y * accY[2 * m + 1];
            }
            Hw[hslot + i * 64] = f2h(fast_tanh(acc));
        }
    }
    __syncthreads();

    // ---- two deep layers: packed fp16 + dot2, ping-pong H16a/H16b ----
    for (int l = 0; l < 2; ++l) {
        // restage deep weights packed fp16: [blk][cpg][s*32+k][j] (cp=cpg*4+j)
        // blk4 = w5 + (s==0 ? w7 : 0) (hp input), blk5 = w6 + (s==1 ? w7 : 0) (hn)
        for (int e = tid; e < 6144; e += 512) {
            int blk = e >> 10;
            int r = e & 1023;
            int cpg = r >> 8;
            int r2 = r & 255;
            int ln = r2 >> 2;
            int j = r2 & 3;
            int ss = ln >> 5, kk = ln & 31;
            int cp = cpg * 4 + j;
            const float* Ws = (ss ? Wnd : Wpd) + l * 7168;
            int rk = blk * 32 + 2 * cp;
            float f0 = Ws[rk * 32 + kk];
            float f1 = Ws[(rk + 1) * 32 + kk];
            if (blk >= 4 && ((blk == 4) == (ss == 0))) {
                f0 += Ws[(192 + 2 * cp) * 32 + kk];
                f1 += Ws[(193 + 2 * cp) * 32 + kk];
            }
            WLu[e] = pkh2(f0, f1);
        }
        __syncthreads();

        const uint32_t* Hin = l ? &H16b[0][0][0][0] : &H16a[0][0][0][0];
        uint16_t* Hout16 = reinterpret_cast<uint16_t*>(
            l ? &H16a[0][0][0][0] : &H16b[0][0][0][0]);

        float U12[10], U34[10], Dd[10];
        #pragma unroll
        for (int i = 0; i < 10; ++i) { U12[i] = 0.f; U34[i] = 0.f; Dd[i] = 0.f; }
        const uint32_t* Wd = &WLu[(s * 32 + k) * 4];   // + blk*1024 + cpg*256
        const uint32_t* Hg = Hin + g * 320;            // [j][cp][2], j stride 32

        for (int cpg = 0; cpg < 4; ++cpg) {
            uint4 w0 = *reinterpret_cast<const uint4*>(Wd + 0 * 1024 + cpg * 256);
            uint4 w1 = *reinterpret_cast<const uint4*>(Wd + 1 * 1024 + cpg * 256);
            uint4 w2 = *reinterpret_cast<const uint4*>(Wd + 2 * 1024 + cpg * 256);
            uint4 w3 = *reinterpret_cast<const uint4*>(Wd + 3 * 1024 + cpg * 256);
            uint4 w4 = *reinterpret_cast<const uint4*>(Wd + 4 * 1024 + cpg * 256);
            uint4 w5 = *reinterpret_cast<const uint4*>(Wd + 5 * 1024 + cpg * 256);
            #pragma unroll
            for (int j = 0; j < 10; ++j) {
                // ha = {hp(c0),hn(c0),hp(c1),hn(c1)}, hb = {hp(c2),hn(c2),hp(c3),hn(c3)}
                uint4 ha = *reinterpret_cast<const uint4*>(Hg + j * 32 + cpg * 8);
                uint4 hb = *reinterpret_cast<const uint4*>(Hg + j * 32 + cpg * 8 + 4);
                U12[j] = dot2(ha.x, w0.x, U12[j]);
                U12[j] = dot2(ha.z, w0.y, U12[j]);
                U12[j] = dot2(hb.x, w0.z, U12[j]);
                U12[j] = dot2(hb.z, w0.w, U12[j]);
                U12[j] = dot2(ha.y, w1.x, U12[j]);
                U12[j] = dot2(ha.w, w1.y, U12[j]);
                U12[j] = dot2(hb.y, w1.z, U12[j]);
                U12[j] = dot2(hb.w, w1.w, U12[j]);
                U34[j] = dot2(ha.x, w2.x, U34[j]);
                U34[j] = dot2(ha.z, w2.y, U34[j]);
                U34[j] = dot2(hb.x, w2.z, U34[j]);
                U34[j] = dot2(hb.z, w2.w, U34[j]);
                U34[j] = dot2(ha.y, w3.x, U34[j]);
                U34[j] = dot2(ha.w, w3.y, U34[j]);
                U34[j] = dot2(hb.y, w3.z, U34[j]);
                U34[j] = dot2(hb.w, w3.w, U34[j]);
                Dd[j]  = dot2(ha.x, w4.x, Dd[j]);
                Dd[j]  = dot2(ha.z, w4.y, Dd[j]);
                Dd[j]  = dot2(hb.x, w4.z, Dd[j]);
                Dd[j]  = dot2(hb.z, w4.w, Dd[j]);
                Dd[j]  = dot2(ha.y, w5.x, Dd[j]);
                Dd[j]  = dot2(ha.w, w5.y, Dd[j]);
                Dd[j]  = dot2(hb.y, w5.z, Dd[j]);
                Dd[j]  = dot2(hb.w, w5.w, Dd[j]);
            }
        }
        float bb = (s ? bnd : bpd)[l * 32 + k];
        const float2* Ap = reinterpret_cast<const float2*>(&As[g][0][0][0]);
        const float2* An = reinterpret_cast<const float2*>(&As[g][1][0][0]);
        #pragma unroll
        for (int i = 0; i < 10; ++i) {
            float acc = Dd[i] + bb;
            #pragma unroll
            for (int m = 0; m < 5; ++m) {
                float2 ap = Ap[i * 5 + m], an = An[i * 5 + m];
                acc += ap.x * U12[2 * m] + ap.y * U12[2 * m + 1]
                     + an.x * U34[2 * m] + an.y * U34[2 * m + 1];
            }
            Hout16[hslot + i * 64] = f2h(fast_tanh(acc));
        }
        __syncthreads();
    }

    // ---- z = cat([h_pos, h_neg], -1) as packed fp16 u32 (final H in H16a) ----
    {
        uint32_t* zb = z + (size_t)bt0 * 320;
        const uint32_t* Hf = &H16a[0][0][0][0];
        for (int e = tid; e < NG * 320; e += 512) {
            int gg = e / 320, r = e - gg * 320;
            int i = r >> 5, m = r & 31;
            zb[e] = Hf[gg * 320 + i * 32 + (m & 15) * 2 + (m >> 4)];
        }
    }
}

// ---------------------------------------------------------------------------
// LSTM v5: 2 barriers/step (was 3). Threads 128..191 stage z[t+1] into LDS
// DURING the activation phase (z and h regions of zh are disjoint) and
// prefetch z[t+2] from global a full step ahead -> HBM latency off the
// critical path. Gate accumulators split 4-deep per game (chain 32 -> 16).
// ---------------------------------------------------------------------------
__global__ __launch_bounds__(256) void lstm_kernel(
    const uint32_t* __restrict__ zin,
    const float* __restrict__ W_ih,
    const float* __restrict__ W_hh,
    const float* __restrict__ b_ih,
    const float* __restrict__ b_hh,
    float* __restrict__ out)
{
    __shared__ __align__(16) uint32_t zh[2][64];  // per game: [z 32 u32 | h 32 u32] fp16
    __shared__ float gbuf[2][256];                // gate pre-activations fp32

    const int tid = threadIdx.x;
    const int p   = blockIdx.x % 10;
    const int b0  = (blockIdx.x / 10) * 2;

    uint32_t wreg[64];   // packed fp16: [z-pairs 0..31 | h-pairs 32..63]
    {
        const float4* wi4 = reinterpret_cast<const float4*>(
            W_ih + ((size_t)p * 256 + tid) * 64);
        const float4* wh4 = reinterpret_cast<const float4*>(
            W_hh + ((size_t)p * 256 + tid) * 64);
        #pragma unroll
        for (int m = 0; m < 16; ++m) {
            float4 v = wi4[m];
            wreg[m * 2 + 0] = pkh2(v.x, v.y);
            wreg[m * 2 + 1] = pkh2(v.z, v.w);
        }
        #pragma unroll
        for (int m = 0; m < 16; ++m) {
            float4 v = wh4[m];
            wreg[32 + m * 2 + 0] = pkh2(v.x, v.y);
            wreg[32 + m * 2 + 1] = pkh2(v.z, v.w);
        }
    }
    const float bias = b_ih[p * 256 + tid] + b_hh[p * 256 + tid];
    const int n = (tid >> 6) & 1, kk = tid & 63;   // activation roles (tid<128)
    const int zn = (tid >> 5) & 1, zk = tid & 31;  // z-stager roles (128<=tid<192)
    float creg = 0.f;
    uint32_t znext = 0;

    if (tid < 64) zh[tid >> 5][32 + (tid & 31)] = 0u;   // h := 0
    if (tid >= 128 && tid < 192) {
        const size_t zb = (size_t)(b0 + zn) * 64;
        zh[zn][zk] = zin[(zb + 0) * 320 + p * 32 + zk];   // z[0]
        znext      = zin[(zb + 1) * 320 + p * 32 + zk];   // prefetch z[1]
    }
    __syncthreads();

    for (int t = 0; t < 64; ++t) {
        // phase B: all 256 threads compute gate row tid for both games
        float a0 = bias, a0b = 0.f, a0c = 0.f, a0d = 0.f;
        float a1 = bias, a1b = 0.f, a1c = 0.f, a1d = 0.f;
        #pragma unroll
        for (int q = 0; q < 16; ++q) {
            uint4 z0 = *reinterpret_cast<const uint4*>(&zh[0][q * 4]);
            uint4 z1 = *reinterpret_cast<const uint4*>(&zh[1][q * 4]);
            a0  = dot2(z0.x, wreg[q * 4 + 0], a0);
            a0b = dot2(z0.y, wreg[q * 4 + 1], a0b);
            a0c = dot2(z0.z, wreg[q * 4 + 2], a0c);
            a0d = dot2(z0.w, wreg[q * 4 + 3], a0d);
            a1  = dot2(z1.x, wreg[q * 4 + 0], a1);
            a1b = dot2(z1.y, wreg[q * 4 + 1], a1b);
            a1c = dot2(z1.z, wreg[q * 4 + 2], a1c);
            a1d = dot2(z1.w, wreg[q * 4 + 3], a1d);
        }
        gbuf[0][tid] = (a0 + a0b) + (a0c + a0d);
        gbuf[1][tid] = (a1 + a1b) + (a1c + a1d);
        __syncthreads();

        // phase A: activation (tid<128) || z[t+1] staging (128<=tid<192)
        if (tid < 128) {
            float gi = gbuf[n][kk];
            float gf = gbuf[n][64 + kk];
            float gg = gbuf[n][128 + kk];
            float go = gbuf[n][192 + kk];
            float cn = sigmoidf_(gf) * creg + sigmoidf_(gi) * fast_tanh(gg);
            float hn = sigmoidf_(go) * fast_tanh(cn);
            creg = cn;
            reinterpret_cast<uint16_t*>(&zh[0][0])[n * 128 + 64 + kk] = f2h(hn);
            out[((size_t)(b0 + n) * 64 + t) * 640 + p * 64 + kk] = hn;
        } else if (tid < 192) {
            if (t < 63) {
                zh[zn][zk] = znext;
                if (t < 62)
                    znext = zin[((size_t)(b0 + zn) * 64 + t + 2) * 320 + p * 32 + zk];
            }
        }
        __syncthreads();
    }
}

extern "C" void kernel_launch(void* const* d_in, const int* in_sizes, int n_in,
                              void* d_out, int out_size, void* d_ws, size_t ws_size,
                              hipStream_t stream) {
    const float* x     = (const float*)d_in[0];
    const float* A_pos = (const float*)d_in[1];
    const float* A_neg = (const float*)d_in[2];
    const float* Wpb   = (const float*)d_in[3];
    const float* bpb   = (const float*)d_in[4];
    const float* Wnb   = (const float*)d_in[5];
    const float* bnb   = (const float*)d_in[6];
    const float* Wpd   = (const float*)d_in[7];
    const float* bpd   = (const float*)d_in[8];
    const float* Wnd   = (const float*)d_in[9];
    const float* bnd   = (const float*)d_in[10];
    const float* Wih   = (const float*)d_in[11];
    const float* Whh   = (const float*)d_in[12];
    const float* bih   = (const float*)d_in[13];
    const float* bhh   = (const float*)d_in[14];

    uint32_t* z = (uint32_t*)d_ws;     // [B,T,P,32] packed fp16 pairs = 20 MB
    float* out  = (float*)d_out;       // [B,T,P,64] fp32 = 40 MB

    sgcn_kernel<<<(Bg * Tg) / NG, 512, 0, stream>>>(
        x, A_pos, A_neg, Wpb, bpb, Wnb, bnb, Wpd, bpd, Wnd, bnd, z);
    lstm_kernel<<<(Bg / 2) * Pg, 256, 0, stream>>>(
        z, Wih, Whh, bih, bhh, out);
}